// Round 7
// baseline (115.262 us; speedup 1.0000x reference)
//
#include <hip/hip_runtime.h>
#include <hip/hip_bf16.h>
#include <math.h>

#define E_N 4096
#define PI_F 3.14159265358979323846f
#define ATH 0.08726646259971647f   /* radians(5.0) */

// distance histogram: 2048 bins over [0,160); quantiles interpolated in-bin
#define NB1 2048
#define SCALE1 12.8f
#define W1 0.078125f
#define SUMSC 16384.0f             /* fixed-point scale 2^14 for per-pair d */
#define MASK44 ((1ull << 44) - 1ull)

// tiling: upper-triangle 128x128 pair tiles -> 528 blocks
#define TILE 128
#define NT   (E_N / TILE)           /* 32 */
#define NBLK (NT * (NT + 1) / 2)    /* 528 */
#define THR1 512                    /* 8 waves/block, ~22KB LDS -> 4 blk/CU */

// hierarchical merge: 8 global hist copies (atomics only -> memory-side
// coherent; NO fences needed anywhere - round-3 lesson: threadfence's L2
// writeback op x waves was 150us; bare vmcnt(0) waits are free)
#define N_HIST 8

// workspace layout (bytes): ctl + hists zeroed by one 128KB memset node
#define O_CTL 0                     /* u32[16]: [0]=ticket */
#define O_H1  64                    /* N_HIST x 2048 u64 packed (cnt<<44)|sum14 */
#define ZBYTES (O_H1 + N_HIST * NB1 * 8)   /* 131136 */

// ---- single kernel: all-pairs -> LDS hist -> merge -> ticketed epilogue ----
__global__ __launch_bounds__(THR1) void pair_hist(const void* __restrict__ posv,
                                                  const int* __restrict__ eidx,
                                                  char* __restrict__ ws,
                                                  unsigned* __restrict__ out)
{
    unsigned* ctl = (unsigned*)(ws + O_CTL);
    unsigned long long* h1 = (unsigned long long*)(ws + O_H1);

    __shared__ float4 rowA[TILE];             // (ang, nx, ny, c)  : 2KB
    __shared__ float  s_cang[TILE];           // col angles        : 512B
    __shared__ float2 s_cmid[TILE];           // col midpoints     : 1KB
    __shared__ unsigned long long s_s64[NB1]; // packed hist       : 16KB
    __shared__ unsigned s_scan[THR1];         // epilogue scan     : 2KB
    __shared__ float   s_vv[3];
    __shared__ float   s_lohi[2];
    __shared__ unsigned s_last;
    __shared__ double  s_dw[THR1 / 64];
    __shared__ unsigned s_flag;

    int tid = threadIdx.x, bid = blockIdx.x;

    // decode triangular tile index -> (tr, tc), tr <= tc (uniform scalar loop)
    int tr = 0, rem = bid;
    while (rem >= NT - tr) { rem -= NT - tr; ++tr; }
    int tc = tr + rem;

    if (tid == 0) s_flag = 0u;
    for (int k = tid; k < NB1; k += THR1) s_s64[k] = 0ull;
    __syncthreads();

    // dtype detect (one uint4/thread = 8 halves): f32 misread as bf16 shows
    // exponent >=137 in mantissa halves; bf16 data in [0,100] never does.
    {
        const uint4* p4 = (const uint4*)posv;
        uint4 v = p4[tid];
        unsigned f = 0;
#pragma unroll
        for (int k = 0; k < 4; ++k) {
            unsigned u = (&v.x)[k];
            if ((((u >> 7) & 0xFFu) >= 137u) || (((u >> 23) & 0xFFu) >= 137u))
                f = 1u;
        }
        if (f) atomicOr(&s_flag, 1u);
    }
    __syncthreads();
    bool isf32 = (s_flag != 0u);

    // geometry for this tile's 128 row edges + 128 col edges (1 edge/thread)
    if (tid < 2 * TILE) {
        bool isCol = tid < TILE;
        int local = isCol ? tid : tid - TILE;
        int e = (isCol ? tc : tr) * TILE + local;
        int s = eidx[e], d2 = eidx[E_N + e];
        float px, py, qx, qy;
        if (isf32) {
            const float* pf = (const float*)posv;
            px = pf[2*s]; py = pf[2*s+1]; qx = pf[2*d2]; qy = pf[2*d2+1];
        } else {
            const __hip_bfloat16* pb = (const __hip_bfloat16*)posv;
            px = __bfloat162float(pb[2*s]); py = __bfloat162float(pb[2*s+1]);
            qx = __bfloat162float(pb[2*d2]); qy = __bfloat162float(pb[2*d2+1]);
        }
        float vx = qx - px, vy = qy - py;
        float len = fmaxf(sqrtf(vx*vx + vy*vy), 1e-8f);
        float dx = vx / len, dy = vy / len;
        float a = fmodf(atan2f(dy, dx), PI_F);
        if (a < 0.0f) a += PI_F;              // python floor-mod -> [0, pi)
        if (isCol) {
            s_cang[local] = a;
            s_cmid[local] = make_float2((px + qx) * 0.5f, (py + qy) * 0.5f);
        } else {
            rowA[local] = make_float4(a, -dy, dx, px * (-dy) + py * dx);
        }
    }
    __syncthreads();

    // 128x128 pair tile: thread -> (row = tid&127, col 32-slice = tid>>7).
    // Angle test reads b32 (broadcast); float2 mid only on ~5.6% hits.
    {
        int r = tid & (TILE - 1);
        int q = tid >> 7;                     // 0..3
        float4 rg = rowA[r];
        float angp = rg.x, nx = rg.y, ny = rg.z, c = rg.w;
        int j0 = q * 32;
        bool diag = (tr == tc);
#pragma unroll 4
        for (int jj = 0; jj < 32; ++jj) {
            int j = j0 + jj;
            if (diag && j <= r) continue;     // strict i<j on diagonal tiles
            float aq = s_cang[j];
            float da = fabsf(angp - aq);
            float circ = fminf(da, PI_F - da);
            if (circ <= ATH) {
                float2 cm = s_cmid[j];
                float d = fabsf(nx * cm.x + ny * cm.y - c);
                int b = (int)(d * SCALE1); if (b > NB1 - 1) b = NB1 - 1;
                // single packed LDS atomic: count in [63:44], sum14 in [43:0]
                atomicAdd(&s_s64[b],
                          (1ull << 44) | (unsigned long long)(d * SUMSC + 0.5f));
            }
        }
    }
    __syncthreads();

    // merge: ONE dense u64 atomic per nonzero bin into this block's copy.
    {
        unsigned long long* myh = h1 + (unsigned)(bid & (N_HIST - 1)) * NB1;
        for (int k = tid; k < NB1; k += THR1) {
            unsigned long long v = s_s64[k];
            if (v) atomicAdd(&myh[k], v);
        }
    }
    // wait for THIS wave's atomic acks (coherence-point arrival). This is a
    // plain counter wait - no cache writeback ops (the round-3 fence killer).
    asm volatile("s_waitcnt vmcnt(0)" ::: "memory");
    __syncthreads();                          // all waves' atomics complete
    if (tid == 0) {
        unsigned tk = __hip_atomic_fetch_add(&ctl[0], 1u, __ATOMIC_RELAXED,
                                             __HIP_MEMORY_SCOPE_AGENT);
        s_last = (tk == NBLK - 1u) ? 1u : 0u;
    }
    __syncthreads();
    if (!s_last) return;

    // ---- epilogue (last block only): agent-scope loads bypass stale L2 ----
    int w = tid >> 6, lane = tid & 63;
    unsigned gl[4]; double S[4];
    {
        unsigned long long vs[4] = {0ull, 0ull, 0ull, 0ull};
#pragma unroll
        for (int c = 0; c < N_HIST; ++c) {
#pragma unroll
            for (int k = 0; k < 4; ++k) {
                vs[k] += __hip_atomic_load(&h1[c * NB1 + 4 * tid + k],
                                           __ATOMIC_RELAXED,
                                           __HIP_MEMORY_SCOPE_AGENT);
            }
        }
#pragma unroll
        for (int k = 0; k < 4; ++k) {
            gl[k] = (unsigned)(vs[k] >> 44);
            S[k]  = (double)(vs[k] & MASK44) * (1.0 / 16384.0);
        }
    }
    unsigned gs = gl[0] + gl[1] + gl[2] + gl[3];
    s_scan[tid] = gs;
    __syncthreads();
    for (int off = 1; off < THR1; off <<= 1) {
        unsigned v = (tid >= off) ? s_scan[tid - off] : 0u;
        __syncthreads();
        s_scan[tid] += v;
        __syncthreads();
    }
    unsigned n = s_scan[THR1 - 1];
    if (n == 0) {
        if (tid == 0) {
            __hip_bfloat16 h = __float2bfloat16(0.0f);
            unsigned short b = *(unsigned short*)&h;
            out[0] = ((unsigned)b << 16) | (unsigned)b;
        }
        return;
    }
    long long q1i = (long long)(n / 4) - 1; if (q1i < 0) q1i = 0;
    long long q3i = (3LL * (long long)n) / 4;
    if (q3i > (long long)n - 1) q3i = (long long)n - 1;
    unsigned rks[3] = { (unsigned)q1i, n / 2, (unsigned)q3i };
    unsigned excl = s_scan[tid] - gs;
    for (int t = 0; t < 3; ++t) {
        unsigned r = rks[t];
        if (r >= excl && r < excl + gs) {
            unsigned cum = excl;
#pragma unroll
            for (int k = 0; k < 4; ++k) {
                unsigned c2 = cum + gl[k];
                if (r < c2) {
                    int b = 4 * tid + k;
                    float rr = (float)(r - cum);
                    // uniform-within-bin interpolated quantile value
                    s_vv[t] = ((float)b + (rr + 0.5f) / (float)gl[k]) * W1;
                    break;
                }
                cum = c2;
            }
        }
    }
    __syncthreads();
    if (tid == 0) {
        float iqr = fmaxf(s_vv[2] - s_vv[0], 1e-6f);
        float mu = s_vv[1];
        float margin = 0.75f * iqr;        // iqr * 0.5 * 1.5
        s_lohi[0] = mu - margin;
        s_lohi[1] = mu + margin;
    }
    __syncthreads();
    float lo = s_lohi[0], hi = s_lohi[1];
    // hinge from (count,sum) per bin; boundary bins via uniform integral
    double H = 0.0;
#pragma unroll
    for (int k = 0; k < 4; ++k) {
        int b = 4 * tid + k;
        unsigned c = gl[k];
        if (!c) continue;
        double Sk = S[k];
        float blo = (float)b * W1, bhi = blo + W1;
        if (bhi <= lo) {
            H += (double)lo * (double)c - Sk;
        } else if (blo >= hi) {
            H += Sk - (double)hi * (double)c;
        } else {
            double cf = (double)c / (double)W1;
            if (blo < lo) {
                float u1 = fminf(bhi, lo);
                double a0 = (double)lo - (double)blo;
                double a1 = (double)lo - (double)u1;
                H += cf * 0.5 * (a0 * a0 - a1 * a1);
            }
            if (bhi > hi) {
                float v0b = fmaxf(blo, hi);
                double b1 = (double)bhi - (double)hi;
                double b0 = (double)v0b - (double)hi;
                H += cf * 0.5 * (b1 * b1 - b0 * b0);
            }
        }
    }
    for (int off = 32; off > 0; off >>= 1) H += __shfl_down(H, off, 64);
    if (lane == 0) s_dw[w] = H;
    __syncthreads();
    if (tid == 0) {
        double tot = 0.0;
        for (int k = 0; k < THR1 / 64; ++k) tot += s_dw[k];
        float loss = (float)(tot / (double)n);
        __hip_bfloat16 h = __float2bfloat16(loss);
        unsigned short b = *(unsigned short*)&h;
        out[0] = ((unsigned)b << 16) | (unsigned)b;   // dtype-hedged scalar write
    }
}

// ============================== launcher ====================================
extern "C" void kernel_launch(void* const* d_in, const int* in_sizes, int n_in,
                              void* d_out, int out_size, void* d_ws, size_t ws_size,
                              hipStream_t stream) {
    const void* pos = d_in[0];
    const int* eidx = (const int*)d_in[2];   // adjacency (d_in[1]) unused
    char* ws = (char*)d_ws;
    unsigned* outp = (unsigned*)d_out;

    hipMemsetAsync(ws, 0, ZBYTES, stream);   // zero ticket + 8 packed hists
    pair_hist<<<NBLK, THR1, 0, stream>>>(pos, eidx, ws, outp);
}

// Round 8
// 107.043 us; speedup vs baseline: 1.0768x; 1.0768x over previous
//
#include <hip/hip_runtime.h>
#include <hip/hip_bf16.h>
#include <math.h>

#define E_N 4096
#define PI_F 3.14159265358979323846f
#define ATH 0.08726646259971647f   /* radians(5.0) */

// distance histogram: 2048 bins over [0,160); quantiles interpolated in-bin
#define NB1 2048
#define SCALE1 12.8f
#define W1 0.078125f
#define SUMSC 16384.0f             /* fixed-point scale 2^14 for per-pair d */
#define MASK44 ((1ull << 44) - 1ull)

// tiling: upper-triangle 128x128 pair tiles -> 528 blocks
#define TILE 128
#define NT   (E_N / TILE)           /* 32 */
#define NBLK (NT * (NT + 1) / 2)    /* 528 */
#define THR1 512                    /* ~20KB LDS -> 4 blk/CU, one sched round */
#define THR2 512

// hierarchical merge: 8 global hist copies; cross-kernel visibility via the
// dispatch boundary (round-4/6 lesson: NO fences/tickets -> no L2 wb ops)
#define N_HIST 8

// workspace layout (bytes): hists zeroed by one 128KB memset node
#define O_H1  0                     /* N_HIST x 2048 u64 packed (cnt<<44)|sum14 */
#define ZBYTES (N_HIST * NB1 * 8)   /* 131072 */

// ---- K1: tiled all-pairs -> LDS hist -> dense merge. No fences/tickets. ---
__global__ __launch_bounds__(THR1) void pair_hist(const void* __restrict__ posv,
                                                  const int* __restrict__ eidx,
                                                  char* __restrict__ ws)
{
    unsigned long long* h1 = (unsigned long long*)(ws + O_H1);

    __shared__ float4 rowA[TILE];             // (ang, nx, ny, c)  : 2KB
    __shared__ float  s_cang[TILE];           // col angles        : 512B
    __shared__ float2 s_cmid[TILE];           // col midpoints     : 1KB
    __shared__ unsigned long long s_s64[NB1]; // packed hist       : 16KB
    __shared__ unsigned s_flag;

    int tid = threadIdx.x, bid = blockIdx.x;

    // decode triangular tile index -> (tr, tc), tr <= tc (uniform scalar loop)
    int tr = 0, rem = bid;
    while (rem >= NT - tr) { rem -= NT - tr; ++tr; }
    int tc = tr + rem;

    if (tid == 0) s_flag = 0u;
    for (int k = tid; k < NB1; k += THR1) s_s64[k] = 0ull;
    __syncthreads();

    // dtype detect (one uint4/thread = 8 halves of first 8192): f32 misread
    // as bf16 halves shows exponent >=137 (|v|>=1024); bf16 in [0,100] never.
    {
        const uint4* p4 = (const uint4*)posv;
        uint4 v = p4[tid];
        unsigned f = 0;
#pragma unroll
        for (int k = 0; k < 4; ++k) {
            unsigned u = (&v.x)[k];
            if ((((u >> 7) & 0xFFu) >= 137u) || (((u >> 23) & 0xFFu) >= 137u))
                f = 1u;
        }
        if (f) atomicOr(&s_flag, 1u);
    }
    __syncthreads();
    bool isf32 = (s_flag != 0u);

    // geometry for this tile's 128 row edges + 128 col edges (1 edge/thread)
    if (tid < 2 * TILE) {
        bool isCol = tid < TILE;
        int local = isCol ? tid : tid - TILE;
        int e = (isCol ? tc : tr) * TILE + local;
        int s = eidx[e], d2 = eidx[E_N + e];
        float px, py, qx, qy;
        if (isf32) {
            const float* pf = (const float*)posv;
            px = pf[2*s]; py = pf[2*s+1]; qx = pf[2*d2]; qy = pf[2*d2+1];
        } else {
            const __hip_bfloat16* pb = (const __hip_bfloat16*)posv;
            px = __bfloat162float(pb[2*s]); py = __bfloat162float(pb[2*s+1]);
            qx = __bfloat162float(pb[2*d2]); qy = __bfloat162float(pb[2*d2+1]);
        }
        float vx = qx - px, vy = qy - py;
        float len = fmaxf(sqrtf(vx*vx + vy*vy), 1e-8f);
        float dx = vx / len, dy = vy / len;
        float a = fmodf(atan2f(dy, dx), PI_F);
        if (a < 0.0f) a += PI_F;              // python floor-mod -> [0, pi)
        if (isCol) {
            s_cang[local] = a;
            s_cmid[local] = make_float2((px + qx) * 0.5f, (py + qy) * 0.5f);
        } else {
            rowA[local] = make_float4(a, -dy, dx, px * (-dy) + py * dx);
        }
    }
    __syncthreads();

    // 128x128 pair tile: thread -> (row = tid&127, col 32-slice = tid>>7).
    // Wave lanes share j -> s_cang[j] is a same-address broadcast (no
    // conflict, b32); float2 midpoint read only on ~5.6% hits.
    {
        int r = tid & (TILE - 1);
        int q = tid >> 7;                     // 0..3
        float4 rg = rowA[r];
        float angp = rg.x, nx = rg.y, ny = rg.z, c = rg.w;
        int j0 = q * 32;
        bool diag = (tr == tc);
#pragma unroll 8
        for (int jj = 0; jj < 32; ++jj) {
            int j = j0 + jj;
            if (diag && j <= r) continue;     // strict i<j on diagonal tiles
            float aq = s_cang[j];
            float da = fabsf(angp - aq);
            float circ = fminf(da, PI_F - da);
            if (circ <= ATH) {
                float2 cm = s_cmid[j];
                float d = fabsf(nx * cm.x + ny * cm.y - c);
                int b = (int)(d * SCALE1); if (b > NB1 - 1) b = NB1 - 1;
                // single packed LDS atomic: count in [63:44], sum14 in [43:0]
                atomicAdd(&s_s64[b],
                          (1ull << 44) | (unsigned long long)(d * SUMSC + 0.5f));
            }
        }
    }
    __syncthreads();

    // merge: ONE dense fire-and-forget u64 atomic per nonzero bin, then exit.
    {
        unsigned long long* myh = h1 + (unsigned)(bid & (N_HIST - 1)) * NB1;
        for (int k = tid; k < NB1; k += THR1) {
            unsigned long long v = s_s64[k];
            if (v) atomicAdd(&myh[k], v);
        }
    }
}

// ---- K2: 1 block. Sum 8 copies, scan, interpolate quantiles, hinge. -------
__global__ __launch_bounds__(THR2) void reduce_ep(const char* __restrict__ ws,
                                                  unsigned* __restrict__ out)
{
    const unsigned long long* h1 = (const unsigned long long*)(ws + O_H1);

    __shared__ unsigned s_scan[THR2];         // scan : 2KB
    __shared__ float   s_vv[3];
    __shared__ float   s_lohi[2];
    __shared__ double  s_dw[THR2 / 64];

    int tid = threadIdx.x;
    int w = tid >> 6, lane = tid & 63;

    // exact integer sum of the 8 hist copies (packed fields cannot carry:
    // cnt <= 2^20 in bits [63:44], sum14 <= ~2^33 in bits [43:0]);
    // 4 bins/thread via two ulonglong2 loads per copy (32B/lane, coalesced)
    unsigned long long vs[4] = {0ull, 0ull, 0ull, 0ull};
    {
        const ulonglong2* hv = (const ulonglong2*)h1;
#pragma unroll
        for (int c = 0; c < N_HIST; ++c) {
            ulonglong2 p0 = hv[c * (NB1 / 2) + 2 * tid];
            ulonglong2 p1 = hv[c * (NB1 / 2) + 2 * tid + 1];
            vs[0] += p0.x; vs[1] += p0.y; vs[2] += p1.x; vs[3] += p1.y;
        }
    }
    unsigned gl[4]; double S[4];
#pragma unroll
    for (int k = 0; k < 4; ++k) {
        gl[k] = (unsigned)(vs[k] >> 44);
        S[k]  = (double)(vs[k] & MASK44) * (1.0 / 16384.0);
    }
    unsigned gs = gl[0] + gl[1] + gl[2] + gl[3];
    s_scan[tid] = gs;
    __syncthreads();
    for (int off = 1; off < THR2; off <<= 1) {
        unsigned v = (tid >= off) ? s_scan[tid - off] : 0u;
        __syncthreads();
        s_scan[tid] += v;
        __syncthreads();
    }
    unsigned n = s_scan[THR2 - 1];
    if (n == 0) {
        if (tid == 0) {
            __hip_bfloat16 h = __float2bfloat16(0.0f);
            unsigned short b = *(unsigned short*)&h;
            out[0] = ((unsigned)b << 16) | (unsigned)b;
        }
        return;
    }
    long long q1i = (long long)(n / 4) - 1; if (q1i < 0) q1i = 0;
    long long q3i = (3LL * (long long)n) / 4;
    if (q3i > (long long)n - 1) q3i = (long long)n - 1;
    unsigned rks[3] = { (unsigned)q1i, n / 2, (unsigned)q3i };
    unsigned excl = s_scan[tid] - gs;
    for (int t = 0; t < 3; ++t) {
        unsigned r = rks[t];
        if (r >= excl && r < excl + gs) {
            unsigned cum = excl;
#pragma unroll
            for (int k = 0; k < 4; ++k) {
                unsigned c2 = cum + gl[k];
                if (r < c2) {
                    int b = 4 * tid + k;
                    float rr = (float)(r - cum);
                    // uniform-within-bin interpolated quantile value
                    s_vv[t] = ((float)b + (rr + 0.5f) / (float)gl[k]) * W1;
                    break;
                }
                cum = c2;
            }
        }
    }
    __syncthreads();
    if (tid == 0) {
        float iqr = fmaxf(s_vv[2] - s_vv[0], 1e-6f);
        float mu = s_vv[1];
        float margin = 0.75f * iqr;        // iqr * 0.5 * 1.5
        s_lohi[0] = mu - margin;
        s_lohi[1] = mu + margin;
    }
    __syncthreads();
    float lo = s_lohi[0], hi = s_lohi[1];
    // hinge from (count,sum) per bin; boundary bins via uniform integral
    double H = 0.0;
#pragma unroll
    for (int k = 0; k < 4; ++k) {
        int b = 4 * tid + k;
        unsigned c = gl[k];
        if (!c) continue;
        double Sk = S[k];
        float blo = (float)b * W1, bhi = blo + W1;
        if (bhi <= lo) {
            H += (double)lo * (double)c - Sk;
        } else if (blo >= hi) {
            H += Sk - (double)hi * (double)c;
        } else {
            double cf = (double)c / (double)W1;
            if (blo < lo) {
                float u1 = fminf(bhi, lo);
                double a0 = (double)lo - (double)blo;
                double a1 = (double)lo - (double)u1;
                H += cf * 0.5 * (a0 * a0 - a1 * a1);
            }
            if (bhi > hi) {
                float v0b = fmaxf(blo, hi);
                double b1 = (double)bhi - (double)hi;
                double b0 = (double)v0b - (double)hi;
                H += cf * 0.5 * (b1 * b1 - b0 * b0);
            }
        }
    }
    for (int off = 32; off > 0; off >>= 1) H += __shfl_down(H, off, 64);
    if (lane == 0) s_dw[w] = H;
    __syncthreads();
    if (tid == 0) {
        double tot = 0.0;
        for (int k = 0; k < THR2 / 64; ++k) tot += s_dw[k];
        float loss = (float)(tot / (double)n);
        __hip_bfloat16 h = __float2bfloat16(loss);
        unsigned short b = *(unsigned short*)&h;
        out[0] = ((unsigned)b << 16) | (unsigned)b;   // dtype-hedged scalar write
    }
}

// ============================== launcher ====================================
extern "C" void kernel_launch(void* const* d_in, const int* in_sizes, int n_in,
                              void* d_out, int out_size, void* d_ws, size_t ws_size,
                              hipStream_t stream) {
    const void* pos = d_in[0];
    const int* eidx = (const int*)d_in[2];   // adjacency (d_in[1]) unused
    char* ws = (char*)d_ws;
    unsigned* outp = (unsigned*)d_out;

    hipMemsetAsync(ws, 0, ZBYTES, stream);   // zero 8 packed hists
    pair_hist<<<NBLK, THR1, 0, stream>>>(pos, eidx, ws);
    reduce_ep<<<1, THR2, 0, stream>>>(ws, outp);
}

// Round 9
// 106.779 us; speedup vs baseline: 1.0794x; 1.0025x over previous
//
#include <hip/hip_runtime.h>
#include <hip/hip_bf16.h>
#include <math.h>

#define E_N 4096
#define PI_F 3.14159265358979323846f
#define ATH 0.08726646259971647f   /* radians(5.0) */

// distance histogram: 2048 bins over [0,160); quantiles interpolated in-bin
#define NB1 2048
#define SCALE1 12.8f
#define W1 0.078125f
#define SUMSC 16384.0f             /* fixed-point scale 2^14 for per-pair d */
#define MASK44 ((1ull << 44) - 1ull)

// tiling: upper-triangle 128x128 pair tiles -> 528 blocks
#define TILE 128
#define NT   (E_N / TILE)           /* 32 */
#define NBLK (NT * (NT + 1) / 2)    /* 528 */
#define THR1 512                    /* ~20KB LDS -> 4 blk/CU, one sched round */
#define THR2 512

// hierarchical merge: 8 global hist copies; cross-kernel visibility via the
// dispatch boundary (round-4/6 lesson: NO fences/tickets -> no L2 wb ops)
#define N_HIST 8

// workspace layout (bytes): hists zeroed by one 128KB memset node
#define O_H1  0                     /* N_HIST x 2048 u64 packed (cnt<<44)|sum14 */
#define ZBYTES (N_HIST * NB1 * 8)   /* 131072 */

// ---- K1: tiled all-pairs -> LDS hist -> dense merge. No fences/tickets. ---
__global__ __launch_bounds__(THR1) void pair_hist(const void* __restrict__ posv,
                                                  const int* __restrict__ eidx,
                                                  char* __restrict__ ws)
{
    unsigned long long* h1 = (unsigned long long*)(ws + O_H1);

    __shared__ float4 rowA[TILE];             // (ang, nx, ny, c)  : 2KB
    __shared__ float4 s_cang4[TILE / 4];      // col angles x4     : 512B
    __shared__ float2 s_cmid[TILE];           // col midpoints     : 1KB
    __shared__ unsigned long long s_s64[NB1]; // packed hist       : 16KB
    __shared__ unsigned s_flag;

    int tid = threadIdx.x, bid = blockIdx.x;

    // decode triangular tile index -> (tr, tc), tr <= tc (uniform scalar loop)
    int tr = 0, rem = bid;
    while (rem >= NT - tr) { rem -= NT - tr; ++tr; }
    int tc = tr + rem;

    if (tid == 0) s_flag = 0u;
    for (int k = tid; k < NB1; k += THR1) s_s64[k] = 0ull;
    __syncthreads();

    // dtype detect (one uint4/thread = 8 halves of first 8192): f32 misread
    // as bf16 halves shows exponent >=137 (|v|>=1024); bf16 in [0,100] never.
    {
        const uint4* p4 = (const uint4*)posv;
        uint4 v = p4[tid];
        unsigned f = 0;
#pragma unroll
        for (int k = 0; k < 4; ++k) {
            unsigned u = (&v.x)[k];
            if ((((u >> 7) & 0xFFu) >= 137u) || (((u >> 23) & 0xFFu) >= 137u))
                f = 1u;
        }
        if (f) atomicOr(&s_flag, 1u);
    }
    __syncthreads();
    bool isf32 = (s_flag != 0u);

    // geometry for this tile's 128 row edges + 128 col edges (1 edge/thread)
    if (tid < 2 * TILE) {
        bool isCol = tid < TILE;
        int local = isCol ? tid : tid - TILE;
        int e = (isCol ? tc : tr) * TILE + local;
        int s = eidx[e], d2 = eidx[E_N + e];
        float px, py, qx, qy;
        if (isf32) {
            const float* pf = (const float*)posv;
            px = pf[2*s]; py = pf[2*s+1]; qx = pf[2*d2]; qy = pf[2*d2+1];
        } else {
            const __hip_bfloat16* pb = (const __hip_bfloat16*)posv;
            px = __bfloat162float(pb[2*s]); py = __bfloat162float(pb[2*s+1]);
            qx = __bfloat162float(pb[2*d2]); qy = __bfloat162float(pb[2*d2+1]);
        }
        float vx = qx - px, vy = qy - py;
        float len = fmaxf(sqrtf(vx*vx + vy*vy), 1e-8f);
        float dx = vx / len, dy = vy / len;
        float a = fmodf(atan2f(dy, dx), PI_F);
        if (a < 0.0f) a += PI_F;              // python floor-mod -> [0, pi)
        if (isCol) {
            ((float*)s_cang4)[local] = a;
            s_cmid[local] = make_float2((px + qx) * 0.5f, (py + qy) * 0.5f);
        } else {
            rowA[local] = make_float4(a, -dy, dx, px * (-dy) + py * dx);
        }
    }
    __syncthreads();

    // 128x128 pair tile: thread -> (row = tid&127, col 32-slice = tid>>7).
    // Col angles read 4-at-a-time via ds_read_b128 (2.4x fewer DS-read
    // cycles than 32x b32); lanes share the group -> broadcast, no conflict.
    // float2 midpoint read only on ~5.6% hits.
    {
        int r = tid & (TILE - 1);
        int q = tid >> 7;                     // 0..3
        float4 rg = rowA[r];
        float angp = rg.x, nx = rg.y, ny = rg.z, c = rg.w;
        int j0 = q * 32;
        bool diag = (tr == tc);
#pragma unroll
        for (int g = 0; g < 8; ++g) {
            float4 av = s_cang4[q * 8 + g];
#pragma unroll
            for (int k = 0; k < 4; ++k) {
                int j = j0 + g * 4 + k;
                if (diag && j <= r) continue; // strict i<j on diagonal tiles
                float aq = (&av.x)[k];
                float da = fabsf(angp - aq);
                float circ = fminf(da, PI_F - da);
                if (circ <= ATH) {
                    float2 cm = s_cmid[j];
                    float d = fabsf(nx * cm.x + ny * cm.y - c);
                    int b = (int)(d * SCALE1); if (b > NB1 - 1) b = NB1 - 1;
                    // packed LDS atomic: count in [63:44], sum14 in [43:0]
                    atomicAdd(&s_s64[b],
                              (1ull << 44) |
                              (unsigned long long)(d * SUMSC + 0.5f));
                }
            }
        }
    }
    __syncthreads();

    // merge: ONE dense fire-and-forget u64 atomic per nonzero bin, then exit.
    {
        unsigned long long* myh = h1 + (unsigned)(bid & (N_HIST - 1)) * NB1;
        for (int k = tid; k < NB1; k += THR1) {
            unsigned long long v = s_s64[k];
            if (v) atomicAdd(&myh[k], v);
        }
    }
}

// ---- K2: 1 block. Sum 8 copies, shfl-scan, quantiles, hinge. --------------
__global__ __launch_bounds__(THR2) void reduce_ep(const char* __restrict__ ws,
                                                  unsigned* __restrict__ out)
{
    const unsigned long long* h1 = (const unsigned long long*)(ws + O_H1);

    __shared__ unsigned s_wsum[THR2 / 64];    // per-wave scan totals
    __shared__ float   s_vv[3];
    __shared__ float   s_lohi[2];
    __shared__ double  s_dw[THR2 / 64];

    int tid = threadIdx.x;
    int w = tid >> 6, lane = tid & 63;

    // exact integer sum of the 8 hist copies (packed fields cannot carry:
    // cnt <= 2^20 in bits [63:44], sum14 <= ~2^33 in bits [43:0]);
    // 4 bins/thread via two ulonglong2 loads per copy (32B/lane, coalesced)
    unsigned long long vs[4] = {0ull, 0ull, 0ull, 0ull};
    {
        const ulonglong2* hv = (const ulonglong2*)h1;
#pragma unroll
        for (int c = 0; c < N_HIST; ++c) {
            ulonglong2 p0 = hv[c * (NB1 / 2) + 2 * tid];
            ulonglong2 p1 = hv[c * (NB1 / 2) + 2 * tid + 1];
            vs[0] += p0.x; vs[1] += p0.y; vs[2] += p1.x; vs[3] += p1.y;
        }
    }
    unsigned gl[4]; double S[4];
#pragma unroll
    for (int k = 0; k < 4; ++k) {
        gl[k] = (unsigned)(vs[k] >> 44);
        S[k]  = (double)(vs[k] & MASK44) * (1.0 / 16384.0);
    }
    unsigned gs = gl[0] + gl[1] + gl[2] + gl[3];

    // inclusive scan of gs: per-wave shfl scan + 8-entry wave fixup
    // (exact u32 adds -> identical results to the former Hillis-Steele)
    unsigned incl = gs;
#pragma unroll
    for (int off = 1; off < 64; off <<= 1) {
        unsigned t = __shfl_up(incl, off, 64);
        if (lane >= off) incl += t;
    }
    if (lane == 63) s_wsum[w] = incl;
    __syncthreads();
    if (tid < THR2 / 64) {
        unsigned x = s_wsum[tid];
#pragma unroll
        for (int off = 1; off < THR2 / 64; off <<= 1) {
            unsigned t = __shfl_up(x, off, 64);
            if (tid >= off) x += t;
        }
        s_wsum[tid] = x;
    }
    __syncthreads();
    if (w > 0) incl += s_wsum[w - 1];
    unsigned n = s_wsum[THR2 / 64 - 1];

    if (n == 0) {
        if (tid == 0) {
            __hip_bfloat16 h = __float2bfloat16(0.0f);
            unsigned short b = *(unsigned short*)&h;
            out[0] = ((unsigned)b << 16) | (unsigned)b;
        }
        return;
    }
    long long q1i = (long long)(n / 4) - 1; if (q1i < 0) q1i = 0;
    long long q3i = (3LL * (long long)n) / 4;
    if (q3i > (long long)n - 1) q3i = (long long)n - 1;
    unsigned rks[3] = { (unsigned)q1i, n / 2, (unsigned)q3i };
    unsigned excl = incl - gs;
    for (int t = 0; t < 3; ++t) {
        unsigned r = rks[t];
        if (r >= excl && r < excl + gs) {
            unsigned cum = excl;
#pragma unroll
            for (int k = 0; k < 4; ++k) {
                unsigned c2 = cum + gl[k];
                if (r < c2) {
                    int b = 4 * tid + k;
                    float rr = (float)(r - cum);
                    // uniform-within-bin interpolated quantile value
                    s_vv[t] = ((float)b + (rr + 0.5f) / (float)gl[k]) * W1;
                    break;
                }
                cum = c2;
            }
        }
    }
    __syncthreads();
    if (tid == 0) {
        float iqr = fmaxf(s_vv[2] - s_vv[0], 1e-6f);
        float mu = s_vv[1];
        float margin = 0.75f * iqr;        // iqr * 0.5 * 1.5
        s_lohi[0] = mu - margin;
        s_lohi[1] = mu + margin;
    }
    __syncthreads();
    float lo = s_lohi[0], hi = s_lohi[1];
    // hinge from (count,sum) per bin; boundary bins via uniform integral
    double H = 0.0;
#pragma unroll
    for (int k = 0; k < 4; ++k) {
        int b = 4 * tid + k;
        unsigned c = gl[k];
        if (!c) continue;
        double Sk = S[k];
        float blo = (float)b * W1, bhi = blo + W1;
        if (bhi <= lo) {
            H += (double)lo * (double)c - Sk;
        } else if (blo >= hi) {
            H += Sk - (double)hi * (double)c;
        } else {
            double cf = (double)c / (double)W1;
            if (blo < lo) {
                float u1 = fminf(bhi, lo);
                double a0 = (double)lo - (double)blo;
                double a1 = (double)lo - (double)u1;
                H += cf * 0.5 * (a0 * a0 - a1 * a1);
            }
            if (bhi > hi) {
                float v0b = fmaxf(blo, hi);
                double b1 = (double)bhi - (double)hi;
                double b0 = (double)v0b - (double)hi;
                H += cf * 0.5 * (b1 * b1 - b0 * b0);
            }
        }
    }
    for (int off = 32; off > 0; off >>= 1) H += __shfl_down(H, off, 64);
    if (lane == 0) s_dw[w] = H;
    __syncthreads();
    if (tid == 0) {
        double tot = 0.0;
        for (int k = 0; k < THR2 / 64; ++k) tot += s_dw[k];
        float loss = (float)(tot / (double)n);
        __hip_bfloat16 h = __float2bfloat16(loss);
        unsigned short b = *(unsigned short*)&h;
        out[0] = ((unsigned)b << 16) | (unsigned)b;   // dtype-hedged scalar write
    }
}

// ============================== launcher ====================================
extern "C" void kernel_launch(void* const* d_in, const int* in_sizes, int n_in,
                              void* d_out, int out_size, void* d_ws, size_t ws_size,
                              hipStream_t stream) {
    const void* pos = d_in[0];
    const int* eidx = (const int*)d_in[2];   // adjacency (d_in[1]) unused
    char* ws = (char*)d_ws;
    unsigned* outp = (unsigned*)d_out;

    hipMemsetAsync(ws, 0, ZBYTES, stream);   // zero 8 packed hists
    pair_hist<<<NBLK, THR1, 0, stream>>>(pos, eidx, ws);
    reduce_ep<<<1, THR2, 0, stream>>>(ws, outp);
}